// Round 20
// baseline (97.090 us; speedup 1.0000x reference)
//
#include <hip/hip_runtime.h>
#include <hip/hip_bf16.h>
#include <math.h>

#define BB 8
#define LL 512
#define CIN 7
#define MARKN 4
#define DM 512
#define DI 1024
#define NOUTC 672
#define NTC 16           // t-chunks of 32

typedef unsigned short ushortT;
typedef __attribute__((ext_vector_type(8))) short short8v;
typedef __attribute__((ext_vector_type(4))) float f32x4;

__device__ __forceinline__ float bf2f(ushortT u){ return __uint_as_float(((unsigned)u)<<16); }
__device__ __forceinline__ ushortT f2bf(float f){ __hip_bfloat16 h = __float2bfloat16(f); return *(ushortT*)&h; }

// ========== k_prep_embed: embed (+per-block stats) | in_proj_w conv | x_proj_w conv ==========
__global__ __launch_bounds__(512) void k_prep_embed(const float* __restrict__ xe,
    const float* __restrict__ xmark, const float* __restrict__ tw,
    const float* __restrict__ tpw, const float* __restrict__ inprojw,
    const float* __restrict__ xpw,
    __hip_bfloat16* __restrict__ xo, ushortT* __restrict__ wbf,
    ushortT* __restrict__ xpwbf, float* __restrict__ mean, float* __restrict__ stdv){
  __shared__ float sw[DM*21];          // 43,008 B
  __shared__ float sxr[10][CIN];
  __shared__ float smr[8][MARKN];
  __shared__ float sMean[8], sInv[8];
  int blk = blockIdx.x, tid = threadIdx.x;
  if(blk < 512){
    int b = blk >> 6;
    int l0 = (blk & 63) << 3;
    int wv = tid >> 6, t2 = tid & 63;
    if(wv < 7){
      int c = wv;
      const float* base = xe + (b*LL)*CIN + c;
      float v[8]; float s = 0.f;
      #pragma unroll
      for(int i=0;i<8;i++){ v[i] = base[(t2 + i*64)*CIN]; s += v[i]; }
      #pragma unroll
      for(int o=32;o>=1;o>>=1) s += __shfl_down(s, o);
      float m = __shfl(s, 0) * (1.0f/LL);
      float vs = 0.f;
      #pragma unroll
      for(int i=0;i<8;i++){ float dv = v[i]-m; vs += dv*dv; }
      #pragma unroll
      for(int o=32;o>=1;o>>=1) vs += __shfl_down(vs, o);
      float var = __shfl(vs, 0) * (1.0f/LL);
      float sd = sqrtf(var + 1e-5f);
      if(t2 == 0){
        sMean[c] = m; sInv[c] = 1.0f/sd;
        if(l0 == 0){ mean[b*CIN+c] = m; stdv[b*CIN+c] = sd; }
      }
    }
    __syncthreads();
    for(int i=tid; i<DM*21; i+=512) sw[i] = tw[i];
    if(tid < 70){
      int r = tid / CIN, c = tid % CIN;
      int ls = (l0 - 1 + r + LL) % LL;
      sxr[r][c] = (xe[(b*LL + ls)*CIN + c] - sMean[c]) * sInv[c];
    } else if(tid >= 128 && tid < 160){
      int i2 = tid - 128; int r = i2 >> 2, m = i2 & 3;
      smr[r][m] = xmark[(b*LL + l0 + r)*MARKN + m];
    }
    __syncthreads();
    int d = tid;
    float wv2[21];
    #pragma unroll
    for(int i=0;i<21;i++) wv2[i] = sw[d*21 + i];
    float tv[4];
    #pragma unroll
    for(int m=0;m<4;m++) tv[m] = tpw[d*MARKN + m];
    float divv = expf((float)(2*(d>>1)) * (-0.0179889460390159843f));
    bool isodd = (d & 1) != 0;
    #pragma unroll
    for(int ll=0; ll<8; ll++){
      float acc = 0.f;
      #pragma unroll
      for(int c=0;c<CIN;c++){
        #pragma unroll
        for(int k=0;k<3;k++) acc += sxr[ll+k][c] * wv2[c*3+k];
      }
      #pragma unroll
      for(int m=0;m<4;m++) acc += smr[ll][m] * tv[m];
      float ang = (float)(l0+ll) * divv;
      acc += isodd ? cosf(ang) : sinf(ang);
      xo[(size_t)(b*LL + l0 + ll)*DM + d] = __float2bfloat16(acc);
    }
  } else if(blk < 1024){
    int i = ((blk-512)*512 + tid)*4;
    float4 v = *(const float4*)(inprojw + i);
    ushort4 pk; pk.x=f2bf(v.x); pk.y=f2bf(v.y); pk.z=f2bf(v.z); pk.w=f2bf(v.w);
    *(ushort4*)(wbf + i) = pk;
  } else {
    int i = ((blk-1024)*512 + tid)*4;
    float4 v = *(const float4*)(xpw + i);
    ushort4 pk; pk.x=f2bf(v.x); pk.y=f2bf(v.y); pk.z=f2bf(v.z); pk.w=f2bf(v.w);
    *(ushort4*)(xpwbf + i) = pk;
  }
}

// ===== k_inproj_dw: in_proj MFMA (+16-row halo) + depthwise conv + silu -> ubf (verified r14) =====
__global__ __launch_bounds__(256) void k_inproj_dw(const ushortT* __restrict__ A,
    const ushortT* __restrict__ Bw, const float* __restrict__ cw,
    const float* __restrict__ cb, ushortT* __restrict__ ubf){
  __shared__ __align__(16) ushortT LDSI[2*144*64 + 2*128*64];  // 69,632 B
#define ASLB(bufi) (LDSI + (bufi)*144*64)
#define BSLB(bufi) (LDSI + 2*144*64 + (bufi)*128*64)
  int tid = threadIdx.x;
  int w = tid >> 6, l = tid & 63;
  int m0 = blockIdx.y * 128, n0 = blockIdx.x * 128;
  int wr = w >> 1, wc = w & 1;
  int hbase = (m0 == 0) ? 0 : m0 - 16;   // halo rows (masked at batch starts via conv lg guard)
  f32x4 acc[4][4] = {};
  f32x4 hacc[4] = {};
  int srow = l >> 3;
  int scolswz = ((l & 7) * 16) ^ (srow << 4);

#define IPD_STAGE(bufi, kt) do{ \
    _Pragma("unroll") \
    for(int i=0;i<4;i++){ \
      int r0 = w*32 + i*8; \
      const ushortT* gA = A + (size_t)(m0 + r0 + srow)*512 + (kt)*64 + (scolswz>>1); \
      const ushortT* gB = Bw + (size_t)(n0 + r0 + srow)*512 + (kt)*64 + (scolswz>>1); \
      __builtin_amdgcn_global_load_lds( \
        (const __attribute__((address_space(1))) unsigned int*)(const void*)gA, \
        (__attribute__((address_space(3))) unsigned int*)(void*)(ASLB(bufi) + (16 + r0)*64), 16, 0, 0); \
      __builtin_amdgcn_global_load_lds( \
        (const __attribute__((address_space(1))) unsigned int*)(const void*)gB, \
        (__attribute__((address_space(3))) unsigned int*)(void*)(BSLB(bufi) + r0*64), 16, 0, 0); \
    } \
    if(w < 2){ \
      int hr0 = w*8; \
      const ushortT* gH = A + (size_t)(hbase + hr0 + srow)*512 + (kt)*64 + (scolswz>>1); \
      __builtin_amdgcn_global_load_lds( \
        (const __attribute__((address_space(1))) unsigned int*)(const void*)gH, \
        (__attribute__((address_space(3))) unsigned int*)(void*)(ASLB(bufi) + hr0*64), 16, 0, 0); \
    } }while(0)

  IPD_STAGE(0, 0);
  __syncthreads();
  int cur = 0;
  for(int kt = 0; kt < 8; ++kt){
    if(kt < 7) IPD_STAGE(cur^1, kt+1);
    #pragma unroll
    for(int kk=0;kk<2;kk++){
      short8v af[4], bfr[4];
      int cb2 = kk*64 + (l>>4)*16;
      #pragma unroll
      for(int mf=0;mf<4;mf++){
        int ar = 16 + wr*64 + mf*16 + (l&15);
        af[mf] = *(const short8v*)(ASLB(cur) + ar*64 + ((cb2 ^ ((ar&7)<<4))>>1));
      }
      #pragma unroll
      for(int nf=0;nf<4;nf++){
        int br = wc*64 + nf*16 + (l&15);
        bfr[nf] = *(const short8v*)(BSLB(cur) + br*64 + ((cb2 ^ ((br&7)<<4))>>1));
      }
      #pragma unroll
      for(int mf=0;mf<4;mf++)
        #pragma unroll
        for(int nf=0;nf<4;nf++)
          acc[mf][nf] = __builtin_amdgcn_mfma_f32_16x16x32_bf16(af[mf], bfr[nf], acc[mf][nf], 0, 0, 0);
      if(w < 2){
        int har = (l&15);
        short8v haf = *(const short8v*)(ASLB(cur) + har*64 + ((cb2 ^ ((har&7)<<4))>>1));
        #pragma unroll
        for(int nf=0;nf<4;nf++)
          hacc[nf] = __builtin_amdgcn_mfma_f32_16x16x32_bf16(haf, bfr[nf], hacc[nf], 0, 0, 0);
      }
    }
    __syncthreads();
    cur ^= 1;
  }
#undef IPD_STAGE
  // epilogue: acc -> bf16 LDS tile sU[144][136], then conv+silu -> ubf
  ushortT* sU = LDSI;
  const int US = 136;
  #pragma unroll
  for(int mf=0;mf<4;mf++){
    int rb = 16 + wr*64 + mf*16 + (l>>4)*4;
    #pragma unroll
    for(int nf=0;nf<4;nf++){
      int col = wc*64 + nf*16 + (l&15);
      #pragma unroll
      for(int r=0;r<4;r++) sU[(rb+r)*US + col] = f2bf(acc[mf][nf][r]);
    }
  }
  if(w < 2){
    int rb = (l>>4)*4;
    #pragma unroll
    for(int nf=0;nf<4;nf++){
      int col = wc*64 + nf*16 + (l&15);
      #pragma unroll
      for(int r=0;r<4;r++) sU[(rb+r)*US + col] = f2bf(hacc[nf][r]);
    }
  }
  __syncthreads();
  int col = tid & 127, rh = tid >> 7;
  const float4 w4 = *(const float4*)(cw + (size_t)(n0+col)*4);
  float bias = cb[n0+col];
  int lbase = m0 & 511;
  for(int R = rh*64; R < rh*64 + 64; ++R){
    int lg = lbase + R;
    float x3 = bf2f(sU[(16+R)*US + col]);
    float x2 = (lg>=1) ? bf2f(sU[(15+R)*US + col]) : 0.f;
    float x1 = (lg>=2) ? bf2f(sU[(14+R)*US + col]) : 0.f;
    float x0 = (lg>=3) ? bf2f(sU[(13+R)*US + col]) : 0.f;
    float a = bias + x0*w4.x + x1*w4.y + x2*w4.z + x3*w4.w;
    float s = a / (1.f + __expf(-a));
    ubf[(size_t)(m0+R)*1024 + n0 + col] = f2bf(s);
  }
#undef ASLB
#undef BSLB
}

// ------- x_proj MFMA GEMM: dbl[4096][64] = ubf @ xpwbf^T; M-tile 32, 128 blocks -------
__global__ __launch_bounds__(256) void k_xproj_mfma(const ushortT* __restrict__ A,
    const ushortT* __restrict__ Bw, float* __restrict__ C){
  __shared__ ushortT Asl[2][32*64];
  __shared__ ushortT Bsl[2][64*64];
  int tid = threadIdx.x;
  int w = tid >> 6, l = tid & 63;
  int m0 = blockIdx.x * 32;
  f32x4 acc[2] = {};
  int srow = l >> 3;
  int scol = ((l & 7) * 16) ^ (srow << 4);

#define XP_STAGE(bufi, kt) do{ \
    { \
      int r0 = w*8; \
      const ushortT* gA = A + (size_t)(m0 + r0 + srow)*1024 + (kt)*64 + (scol>>1); \
      __builtin_amdgcn_global_load_lds( \
        (const __attribute__((address_space(1))) unsigned int*)(const void*)gA, \
        (__attribute__((address_space(3))) unsigned int*)(void*)(Asl[bufi] + r0*64), 16, 0, 0); \
    } \
    _Pragma("unroll") \
    for(int i=0;i<2;i++){ \
      int r0 = w*16 + i*8; \
      const ushortT* gB = Bw + (size_t)(r0 + srow)*1024 + (kt)*64 + (scol>>1); \
      __builtin_amdgcn_global_load_lds( \
        (const __attribute__((address_space(1))) unsigned int*)(const void*)gB, \
        (__attribute__((address_space(3))) unsigned int*)(void*)(Bsl[bufi] + r0*64), 16, 0, 0); \
    } }while(0)

  XP_STAGE(0, 0);
  __syncthreads();
  int cur = 0;
  for(int kt = 0; kt < 16; ++kt){
    if(kt < 15) XP_STAGE(cur^1, kt+1);
    #pragma unroll
    for(int kk=0;kk<2;kk++){
      int cb = kk*64 + (l>>4)*16;
      int ar = (w&1)*16 + (l&15);
      short8v af = *(const short8v*)(Asl[cur] + ar*64 + ((cb ^ ((ar&7)<<4))>>1));
      #pragma unroll
      for(int nf=0;nf<2;nf++){
        int br = (w>>1)*32 + nf*16 + (l&15);
        short8v bfv = *(const short8v*)(Bsl[cur] + br*64 + ((cb ^ ((br&7)<<4))>>1));
        acc[nf] = __builtin_amdgcn_mfma_f32_16x16x32_bf16(af, bfv, acc[nf], 0, 0, 0);
      }
    }
    __syncthreads();
    cur ^= 1;
  }
#undef XP_STAGE
  int rbase = m0 + (w&1)*16 + (l>>4)*4;
  #pragma unroll
  for(int nf=0;nf<2;nf++){
    int col = (w>>1)*32 + nf*16 + (l&15);
    #pragma unroll
    for(int r=0;r<4;r++)
      C[(size_t)(rbase+r)*64 + col] = acc[nf][r];
  }
}

// ---------------- scan chunk (dt fused): 32-step chunks, LDS-staged dbl, grid (16,4,8) ----------------
__global__ __launch_bounds__(256) void k_scan_chunk(const float* __restrict__ dbl,
    const ushortT* __restrict__ ubf, const float* __restrict__ dtw,
    const float* __restrict__ dtb, const float* __restrict__ alog,
    float4* __restrict__ P4, float4* __restrict__ Q4){
  int tc = blockIdx.x;                 // 16 t-chunks of 32
  int dgrp = blockIdx.y;               // 4 groups of 256 d
  int b = blockIdx.z;                  // 8
  int tid = threadIdx.x;               // 256
  int d = dgrp*256 + tid;
  __shared__ float sD[32][68];         // dbl rows: cols 0-31 dt_low, 32-47 B, 48-63 C
  #pragma unroll
  for(int j=0;j<2;j++){
    int idx = j*256 + tid;
    int row = idx >> 4, q = idx & 15;
    float4 v = *(const float4*)(dbl + (size_t)(b*LL + tc*32 + row)*64 + q*4);
    *(float4*)(&sD[row][q*4]) = v;
  }
  float wdt[32];
  #pragma unroll
  for(int r4=0;r4<8;r4++){
    float4 v = *(const float4*)(dtw + (size_t)d*32 + r4*4);
    wdt[r4*4]=v.x; wdt[r4*4+1]=v.y; wdt[r4*4+2]=v.z; wdt[r4*4+3]=v.w;
  }
  float bias = dtb[d];
  float Ad[16];
  {
    float4 a0 = *(const float4*)(alog + d*16);
    float4 a1 = *(const float4*)(alog + d*16 + 4);
    float4 a2 = *(const float4*)(alog + d*16 + 8);
    float4 a3 = *(const float4*)(alog + d*16 + 12);
    Ad[0]=-__expf(a0.x); Ad[1]=-__expf(a0.y); Ad[2]=-__expf(a0.z); Ad[3]=-__expf(a0.w);
    Ad[4]=-__expf(a1.x); Ad[5]=-__expf(a1.y); Ad[6]=-__expf(a1.z); Ad[7]=-__expf(a1.w);
    Ad[8]=-__expf(a2.x); Ad[9]=-__expf(a2.y); Ad[10]=-__expf(a2.z); Ad[11]=-__expf(a2.w);
    Ad[12]=-__expf(a3.x); Ad[13]=-__expf(a3.y); Ad[14]=-__expf(a3.z); Ad[15]=-__expf(a3.w);
  }
  __syncthreads();
  float h[16];
  #pragma unroll
  for(int n=0;n<16;n++) h[n] = 0.f;
  float Ss = 0.f;
  const ushortT* up = ubf + (size_t)(b*LL + tc*32)*1024 + d;
  #pragma unroll 2
  for(int t=0;t<32;t++){
    float a2 = bias;
    #pragma unroll
    for(int r=0;r<32;r++) a2 += sD[t][r]*wdt[r];
    float dtv = (a2 > 20.f) ? a2 : __logf(1.f + __expf(a2));
    float uv = bf2f(up[(size_t)t*1024]);
    float wt = dtv * uv;
    Ss += dtv;
    #pragma unroll
    for(int n=0;n<16;n++){
      float e = __expf(dtv * Ad[n]);
      h[n] = h[n]*e + wt*sD[t][32+n];
    }
  }
  size_t base4 = (size_t)(tc*8 + b)*4*1024 + d;
  #pragma unroll
  for(int n4=0;n4<4;n4++){
    Q4[base4 + n4*1024] = make_float4(h[n4*4], h[n4*4+1], h[n4*4+2], h[n4*4+3]);
    P4[base4 + n4*1024] = make_float4(__expf(Ss*Ad[n4*4]), __expf(Ss*Ad[n4*4+1]),
                                      __expf(Ss*Ad[n4*4+2]), __expf(Ss*Ad[n4*4+3]));
  }
}

// ------- combine chunks + z_last dot + C-dot + gating -> yv; 4 lanes per (b,d) unit -------
__global__ __launch_bounds__(256) void k_scan_combine(const float4* __restrict__ P4,
    const float4* __restrict__ Q4, const float* __restrict__ dbl,
    const ushortT* __restrict__ ubf, const ushortT* __restrict__ xbf,
    const ushortT* __restrict__ wbf, const float* __restrict__ Dp,
    float* __restrict__ yv){
  int tid = threadIdx.x;
  int unit = blockIdx.x*64 + (tid>>2);     // 8192 units
  int sub = tid & 3;
  int b = unit >> 10, d = unit & 1023;
  const ushortT* xr = xbf + (size_t)(b*LL + LL-1)*512 + sub*128;
  const ushortT* wr = wbf + (size_t)(1024 + d)*512 + sub*128;
  float zl = 0.f;
  #pragma unroll
  for(int k=0;k<128;k+=8){
    short8v xv = *(const short8v*)(xr + k);
    short8v wv = *(const short8v*)(wr + k);
    #pragma unroll
    for(int j=0;j<8;j++) zl += bf2f((ushortT)xv[j])*bf2f((ushortT)wv[j]);
  }
  zl += __shfl_xor(zl, 1);
  zl += __shfl_xor(zl, 2);
  float h0=0.f, h1=0.f, h2=0.f, h3=0.f;
  #pragma unroll
  for(int c=0;c<NTC;c++){
    size_t idx = (size_t)(c*8 + b)*4*1024 + sub*1024 + d;
    float4 pv = P4[idx];
    float4 qv = Q4[idx];
    h0 = pv.x*h0 + qv.x;
    h1 = pv.y*h1 + qv.y;
    h2 = pv.z*h2 + qv.z;
    h3 = pv.w*h3 + qv.w;
  }
  const float* Crow = dbl + (size_t)(b*LL + LL-1)*64 + 48 + sub*4;
  float y = Crow[0]*h0 + Crow[1]*h1 + Crow[2]*h2 + Crow[3]*h3;
  y += __shfl_xor(y, 1);
  y += __shfl_xor(y, 2);
  if(sub == 0){
    float ul = bf2f(ubf[(size_t)(b*LL + LL-1)*1024 + d]);
    float sz = zl / (1.f + __expf(-zl));
    yv[b*1024 + d] = (y + ul*Dp[d]) * sz;
  }
}

// ---------------- out_proj (last step only): xout[8][512] ----------------
__global__ __launch_bounds__(256) void k_outproj(const float* __restrict__ yv,
    const float* __restrict__ W, float* __restrict__ xout){
  int tid = threadIdx.x;
  int j = blockIdx.x*8 + (tid>>5);     // 64 blocks -> 512 outputs
  int ks = tid & 31;
  float a[8] = {};
  #pragma unroll
  for(int t=0;t<8;t++){
    int k = ks*4 + t*128;
    float4 wv = *(const float4*)(W + (size_t)j*1024 + k);
    #pragma unroll
    for(int b=0;b<8;b++){
      float4 xv = *(const float4*)(yv + b*1024 + k);
      a[b] += xv.x*wv.x + xv.y*wv.y + xv.z*wv.z + xv.w*wv.w;
    }
  }
  #pragma unroll
  for(int b=0;b<8;b++){
    #pragma unroll
    for(int o=16;o>=1;o>>=1) a[b] += __shfl_xor(a[b], o);
  }
  if(ks==0){
    #pragma unroll
    for(int b=0;b<8;b++) xout[b*512 + j] = a[b];
  }
}

// ---------------- head + denorm -> out[8][96][7] ----------------
__global__ __launch_bounds__(256) void k_head(const float* __restrict__ xout,
    const float* __restrict__ W, const float* __restrict__ hb,
    const float* __restrict__ mean, const float* __restrict__ stdv,
    float* __restrict__ out){
  int tid = threadIdx.x;
  int o = blockIdx.x*8 + (tid>>5);     // 84 blocks -> 672 outputs
  int ks = tid & 31;
  float a[8] = {};
  #pragma unroll
  for(int t=0;t<4;t++){
    int k = ks*4 + t*128;
    float4 wv = *(const float4*)(W + (size_t)o*512 + k);
    #pragma unroll
    for(int b=0;b<8;b++){
      float4 xv = *(const float4*)(xout + b*512 + k);
      a[b] += xv.x*wv.x + xv.y*wv.y + xv.z*wv.z + xv.w*wv.w;
    }
  }
  #pragma unroll
  for(int b=0;b<8;b++){
    #pragma unroll
    for(int oo=16;oo>=1;oo>>=1) a[b] += __shfl_xor(a[b], oo);
  }
  if(ks==0){
    int c = o % 7;
    #pragma unroll
    for(int b=0;b<8;b++){
      float v = a[b] + hb[o];
      out[b*NOUTC + o] = v * stdv[b*CIN + c] + mean[b*CIN + c];
    }
  }
}

extern "C" void kernel_launch(void* const* d_in, const int* in_sizes, int n_in,
                              void* d_out, int out_size, void* d_ws, size_t ws_size,
                              hipStream_t stream) {
  const float* x_enc   = (const float*)d_in[0];
  const float* x_mark  = (const float*)d_in[1];
  const float* tconvw  = (const float*)d_in[4];
  const float* tempw   = (const float*)d_in[5];
  const float* inprojw = (const float*)d_in[6];
  const float* convw   = (const float*)d_in[7];
  const float* convb   = (const float*)d_in[8];
  const float* xprojw  = (const float*)d_in[9];
  const float* dtw     = (const float*)d_in[10];
  const float* dtb     = (const float*)d_in[11];
  const float* alog    = (const float*)d_in[12];
  const float* dpar    = (const float*)d_in[13];
  const float* outw    = (const float*)d_in[14];
  const float* headw   = (const float*)d_in[15];
  const float* headb   = (const float*)d_in[16];

  float* ws    = (float*)d_ws;
  float* mean  = ws;                          // 64
  float* stdv  = ws + 64;                     // 64 -> 128
  ushortT* xbf = (ushortT*)(ws + 128);        // [4096][512]  bf16 -> 1,048,704
  ushortT* wbf = (ushortT*)(ws + 1048704);    // [2048][512]  bf16 -> 1,572,992
  ushortT* xpwbf=(ushortT*)(ws + 1572992);    // [64][1024]   bf16 -> 1,605,760
  ushortT* ubf = (ushortT*)(ws + 1605760);    // [4096][1024] bf16 -> 3,702,912
  float* dbl   = ws + 3702912;                // [4096][64]   f32 -> 3,965,056
  float4* P4   = (float4*)(ws + 3965056);     // 524,288 float4 -> 6,062,208
  float4* Q4   = (float4*)(ws + 6062208);     // -> 8,159,360
  float* yv    = ws + 8159360;                // 8,192 -> 8,167,552
  float* xout  = ws + 8167552;                // 4,096 -> 8,171,648
  float* out   = (float*)d_out;

  k_prep_embed<<<1056, 512, 0, stream>>>(x_enc, x_mark, tconvw, tempw, inprojw, xprojw,
                                         (__hip_bfloat16*)xbf, wbf, xpwbf, mean, stdv);
  k_inproj_dw<<<dim3(8, 32), 256, 0, stream>>>(xbf, wbf, convw, convb, ubf);
  k_xproj_mfma<<<128, 256, 0, stream>>>(ubf, xpwbf, dbl);
  k_scan_chunk<<<dim3(NTC, 4, 8), 256, 0, stream>>>(dbl, ubf, dtw, dtb, alog, P4, Q4);
  k_scan_combine<<<128, 256, 0, stream>>>(P4, Q4, dbl, ubf, xbf, wbf, dpar, yv);
  k_outproj<<<64, 256, 0, stream>>>(yv, outw, xout);
  k_head  <<<84, 256, 0, stream>>>(xout, headw, headb, mean, stdv, out);
}

// Round 23
// 88.809 us; speedup vs baseline: 1.0932x; 1.0932x over previous
//
#include <hip/hip_runtime.h>
#include <hip/hip_bf16.h>
#include <math.h>

#define BB 8
#define LL 512
#define CIN 7
#define MARKN 4
#define DM 512
#define DI 1024
#define NOUTC 672
#define NTC 16           // t-chunks of 32

typedef unsigned short ushortT;
typedef __attribute__((ext_vector_type(8))) short short8v;
typedef __attribute__((ext_vector_type(4))) float f32x4;

__device__ __forceinline__ float bf2f(ushortT u){ return __uint_as_float(((unsigned)u)<<16); }
__device__ __forceinline__ ushortT f2bf(float f){ __hip_bfloat16 h = __float2bfloat16(f); return *(ushortT*)&h; }

// ========== k_prep_embed: embed (+per-block stats) | in_proj_w conv | x_proj_w conv ==========
__global__ __launch_bounds__(512) void k_prep_embed(const float* __restrict__ xe,
    const float* __restrict__ xmark, const float* __restrict__ tw,
    const float* __restrict__ tpw, const float* __restrict__ inprojw,
    const float* __restrict__ xpw,
    __hip_bfloat16* __restrict__ xo, ushortT* __restrict__ wbf,
    ushortT* __restrict__ xpwbf, float* __restrict__ mean, float* __restrict__ stdv){
  __shared__ float sw[DM*21];          // 43,008 B
  __shared__ float sxr[10][CIN];
  __shared__ float smr[8][MARKN];
  __shared__ float sMean[8], sInv[8];
  int blk = blockIdx.x, tid = threadIdx.x;
  if(blk < 512){
    int b = blk >> 6;
    int l0 = (blk & 63) << 3;
    int wv = tid >> 6, t2 = tid & 63;
    if(wv < 7){
      int c = wv;
      const float* base = xe + (b*LL)*CIN + c;
      float v[8]; float s = 0.f;
      #pragma unroll
      for(int i=0;i<8;i++){ v[i] = base[(t2 + i*64)*CIN]; s += v[i]; }
      #pragma unroll
      for(int o=32;o>=1;o>>=1) s += __shfl_down(s, o);
      float m = __shfl(s, 0) * (1.0f/LL);
      float vs = 0.f;
      #pragma unroll
      for(int i=0;i<8;i++){ float dv = v[i]-m; vs += dv*dv; }
      #pragma unroll
      for(int o=32;o>=1;o>>=1) vs += __shfl_down(vs, o);
      float var = __shfl(vs, 0) * (1.0f/LL);
      float sd = sqrtf(var + 1e-5f);
      if(t2 == 0){
        sMean[c] = m; sInv[c] = 1.0f/sd;
        if(l0 == 0){ mean[b*CIN+c] = m; stdv[b*CIN+c] = sd; }
      }
    }
    __syncthreads();
    for(int i=tid; i<DM*21; i+=512) sw[i] = tw[i];
    if(tid < 70){
      int r = tid / CIN, c = tid % CIN;
      int ls = (l0 - 1 + r + LL) % LL;
      sxr[r][c] = (xe[(b*LL + ls)*CIN + c] - sMean[c]) * sInv[c];
    } else if(tid >= 128 && tid < 160){
      int i2 = tid - 128; int r = i2 >> 2, m = i2 & 3;
      smr[r][m] = xmark[(b*LL + l0 + r)*MARKN + m];
    }
    __syncthreads();
    int d = tid;
    float wv2[21];
    #pragma unroll
    for(int i=0;i<21;i++) wv2[i] = sw[d*21 + i];
    float tv[4];
    #pragma unroll
    for(int m=0;m<4;m++) tv[m] = tpw[d*MARKN + m];
    float divv = expf((float)(2*(d>>1)) * (-0.0179889460390159843f));
    bool isodd = (d & 1) != 0;
    #pragma unroll
    for(int ll=0; ll<8; ll++){
      float acc = 0.f;
      #pragma unroll
      for(int c=0;c<CIN;c++){
        #pragma unroll
        for(int k=0;k<3;k++) acc += sxr[ll+k][c] * wv2[c*3+k];
      }
      #pragma unroll
      for(int m=0;m<4;m++) acc += smr[ll][m] * tv[m];
      float ang = (float)(l0+ll) * divv;
      acc += isodd ? cosf(ang) : sinf(ang);
      xo[(size_t)(b*LL + l0 + ll)*DM + d] = __float2bfloat16(acc);
    }
  } else if(blk < 1024){
    int i = ((blk-512)*512 + tid)*4;
    float4 v = *(const float4*)(inprojw + i);
    ushort4 pk; pk.x=f2bf(v.x); pk.y=f2bf(v.y); pk.z=f2bf(v.z); pk.w=f2bf(v.w);
    *(ushort4*)(wbf + i) = pk;
  } else {
    int i = ((blk-1024)*512 + tid)*4;
    float4 v = *(const float4*)(xpw + i);
    ushort4 pk; pk.x=f2bf(v.x); pk.y=f2bf(v.y); pk.z=f2bf(v.z); pk.w=f2bf(v.w);
    *(ushort4*)(xpwbf + i) = pk;
  }
}

// ---------------- in_proj MFMA GEMM: xpbf[4096][1024](bf16) = Xbf @ Wbf[0:1024]^T ----------------
__global__ __launch_bounds__(256) void k_inproj_mfma(const ushortT* __restrict__ A,
    const ushortT* __restrict__ Bw, ushortT* __restrict__ C){
  __shared__ ushortT Asl[2][128*64];
  __shared__ ushortT Bsl[2][128*64];
  int tid = threadIdx.x;
  int w = tid >> 6, l = tid & 63;
  int m0 = blockIdx.y * 128, n0 = blockIdx.x * 128;
  int wr = w >> 1, wc = w & 1;
  f32x4 acc[4][4] = {};
  int srow = l >> 3;
  int scolswz = ((l & 7) * 16) ^ (srow << 4);

#define IP_STAGE(bufi, kt) do{ \
    _Pragma("unroll") \
    for(int i=0;i<4;i++){ \
      int r0 = w*32 + i*8; \
      int r = r0 + srow; \
      const ushortT* gA = A + (size_t)(m0 + r)*512 + (kt)*64 + (scolswz>>1); \
      const ushortT* gB = Bw + (size_t)(n0 + r)*512 + (kt)*64 + (scolswz>>1); \
      __builtin_amdgcn_global_load_lds( \
        (const __attribute__((address_space(1))) unsigned int*)(const void*)gA, \
        (__attribute__((address_space(3))) unsigned int*)(void*)(Asl[bufi] + r0*64), 16, 0, 0); \
      __builtin_amdgcn_global_load_lds( \
        (const __attribute__((address_space(1))) unsigned int*)(const void*)gB, \
        (__attribute__((address_space(3))) unsigned int*)(void*)(Bsl[bufi] + r0*64), 16, 0, 0); \
    } }while(0)

  IP_STAGE(0, 0);
  __syncthreads();
  int cur = 0;
  for(int kt = 0; kt < 8; ++kt){
    if(kt < 7) IP_STAGE(cur^1, kt+1);
    #pragma unroll
    for(int kk=0;kk<2;kk++){
      short8v af[4], bfr[4];
      int cb = kk*64 + (l>>4)*16;
      #pragma unroll
      for(int mf=0;mf<4;mf++){
        int ar = wr*64 + mf*16 + (l&15);
        af[mf] = *(const short8v*)(Asl[cur] + ar*64 + ((cb ^ ((ar&7)<<4))>>1));
      }
      #pragma unroll
      for(int nf=0;nf<4;nf++){
        int br = wc*64 + nf*16 + (l&15);
        bfr[nf] = *(const short8v*)(Bsl[cur] + br*64 + ((cb ^ ((br&7)<<4))>>1));
      }
      #pragma unroll
      for(int mf=0;mf<4;mf++)
        #pragma unroll
        for(int nf=0;nf<4;nf++)
          acc[mf][nf] = __builtin_amdgcn_mfma_f32_16x16x32_bf16(af[mf], bfr[nf], acc[mf][nf], 0, 0, 0);
    }
    __syncthreads();
    cur ^= 1;
  }
#undef IP_STAGE
  #pragma unroll
  for(int mf=0;mf<4;mf++){
    int rbase = m0 + wr*64 + mf*16 + (l>>4)*4;
    #pragma unroll
    for(int nf=0;nf<4;nf++){
      int col = n0 + wc*64 + nf*16 + (l&15);
      #pragma unroll
      for(int r=0;r<4;r++)
        C[(size_t)(rbase+r)*1024 + col] = f2bf(acc[mf][nf][r]);
    }
  }
}

// ---------------- causal depthwise conv (D_CONV=4) + silu: xpbf(bf16) -> ubf (bf16) ----------------
__global__ __launch_bounds__(1024) void k_dwconv(const ushortT* __restrict__ xpbf,
    const float* __restrict__ cw, const float* __restrict__ cb,
    ushortT* __restrict__ ubf){
  int blk = blockIdx.x;                 // 256 = 8 b * 32 lchunks
  int b = blk >> 5, l0 = (blk & 31) * 16;
  int d = threadIdx.x;                  // 1024
  const float4 w4 = *(const float4*)(cw + d*4);
  float bias = cb[d];
  const ushortT* base = xpbf + (size_t)(b*LL + l0)*1024 + d;
  float x0=0.f, x1=0.f, x2=0.f;
  if(l0 > 0){
    x0 = bf2f(base[-3*1024]); x1 = bf2f(base[-2*1024]); x2 = bf2f(base[-1*1024]);
  }
  #pragma unroll
  for(int ll=0; ll<16; ++ll){
    float x3 = bf2f(base[(size_t)ll*1024]);
    float acc = bias + x0*w4.x + x1*w4.y + x2*w4.z + x3*w4.w;
    float s = acc / (1.f + __expf(-acc));
    ubf[(size_t)(b*LL + l0 + ll)*1024 + d] = f2bf(s);
    x0 = x1; x1 = x2; x2 = x3;
  }
}

// ------- x_proj MFMA GEMM: dbl[4096][64] = ubf @ xpwbf^T; M-tile 32, 128 blocks -------
// wave w: rows (w&1)*16..+16, cols (w>>1)*32..+32 (2 fragments)
__global__ __launch_bounds__(256) void k_xproj_mfma(const ushortT* __restrict__ A,
    const ushortT* __restrict__ Bw, float* __restrict__ C){
  __shared__ ushortT Asl[2][32*64];
  __shared__ ushortT Bsl[2][64*64];
  int tid = threadIdx.x;
  int w = tid >> 6, l = tid & 63;
  int m0 = blockIdx.x * 32;
  f32x4 acc[2] = {};
  int srow = l >> 3;
  int scol = ((l & 7) * 16) ^ (srow << 4);

#define XP_STAGE(bufi, kt) do{ \
    { \
      int r0 = w*8; \
      const ushortT* gA = A + (size_t)(m0 + r0 + srow)*1024 + (kt)*64 + (scol>>1); \
      __builtin_amdgcn_global_load_lds( \
        (const __attribute__((address_space(1))) unsigned int*)(const void*)gA, \
        (__attribute__((address_space(3))) unsigned int*)(void*)(Asl[bufi] + r0*64), 16, 0, 0); \
    } \
    _Pragma("unroll") \
    for(int i=0;i<2;i++){ \
      int r0 = w*16 + i*8; \
      const ushortT* gB = Bw + (size_t)(r0 + srow)*1024 + (kt)*64 + (scol>>1); \
      __builtin_amdgcn_global_load_lds( \
        (const __attribute__((address_space(1))) unsigned int*)(const void*)gB, \
        (__attribute__((address_space(3))) unsigned int*)(void*)(Bsl[bufi] + r0*64), 16, 0, 0); \
    } }while(0)

  XP_STAGE(0, 0);
  __syncthreads();
  int cur = 0;
  for(int kt = 0; kt < 16; ++kt){
    if(kt < 15) XP_STAGE(cur^1, kt+1);
    #pragma unroll
    for(int kk=0;kk<2;kk++){
      int cb = kk*64 + (l>>4)*16;
      int ar = (w&1)*16 + (l&15);
      short8v af = *(const short8v*)(Asl[cur] + ar*64 + ((cb ^ ((ar&7)<<4))>>1));
      #pragma unroll
      for(int nf=0;nf<2;nf++){
        int br = (w>>1)*32 + nf*16 + (l&15);
        short8v bfv = *(const short8v*)(Bsl[cur] + br*64 + ((cb ^ ((br&7)<<4))>>1));
        acc[nf] = __builtin_amdgcn_mfma_f32_16x16x32_bf16(af, bfv, acc[nf], 0, 0, 0);
      }
    }
    __syncthreads();
    cur ^= 1;
  }
#undef XP_STAGE
  int rbase = m0 + (w&1)*16 + (l>>4)*4;
  #pragma unroll
  for(int nf=0;nf<2;nf++){
    int col = (w>>1)*32 + nf*16 + (l&15);
    #pragma unroll
    for(int r=0;r<4;r++)
      C[(size_t)(rbase+r)*64 + col] = acc[nf][r];
  }
}

// ---------------- scan chunk (dt fused): 32-step chunks, grid (16,4,8) ----------------
__global__ __launch_bounds__(256) void k_scan_chunk(const float* __restrict__ dbl,
    const ushortT* __restrict__ ubf, const float* __restrict__ dtw,
    const float* __restrict__ dtb, const float* __restrict__ alog,
    float4* __restrict__ P4, float4* __restrict__ Q4){
  int tc = blockIdx.x;                 // 16 t-chunks of 32
  int dgrp = blockIdx.y;               // 4 groups of 256 d
  int b = blockIdx.z;                  // 8
  int tid = threadIdx.x;               // 256
  int d = dgrp*256 + tid;
  __shared__ float sD[32][68];         // dbl rows: cols 0-31 dt_low, 32-47 B, 48-63 C
  #pragma unroll
  for(int j=0;j<2;j++){
    int idx = j*256 + tid;
    int row = idx >> 4, q = idx & 15;
    float4 v = *(const float4*)(dbl + (size_t)(b*LL + tc*32 + row)*64 + q*4);
    *(float4*)(&sD[row][q*4]) = v;
  }
  float wdt[32];
  #pragma unroll
  for(int r4=0;r4<8;r4++){
    float4 v = *(const float4*)(dtw + (size_t)d*32 + r4*4);
    wdt[r4*4]=v.x; wdt[r4*4+1]=v.y; wdt[r4*4+2]=v.z; wdt[r4*4+3]=v.w;
  }
  float bias = dtb[d];
  float Ad[16];
  {
    float4 a0 = *(const float4*)(alog + d*16);
    float4 a1 = *(const float4*)(alog + d*16 + 4);
    float4 a2 = *(const float4*)(alog + d*16 + 8);
    float4 a3 = *(const float4*)(alog + d*16 + 12);
    Ad[0]=-__expf(a0.x); Ad[1]=-__expf(a0.y); Ad[2]=-__expf(a0.z); Ad[3]=-__expf(a0.w);
    Ad[4]=-__expf(a1.x); Ad[5]=-__expf(a1.y); Ad[6]=-__expf(a1.z); Ad[7]=-__expf(a1.w);
    Ad[8]=-__expf(a2.x); Ad[9]=-__expf(a2.y); Ad[10]=-__expf(a2.z); Ad[11]=-__expf(a2.w);
    Ad[12]=-__expf(a3.x); Ad[13]=-__expf(a3.y); Ad[14]=-__expf(a3.z); Ad[15]=-__expf(a3.w);
  }
  __syncthreads();
  float h[16];
  #pragma unroll
  for(int n=0;n<16;n++) h[n] = 0.f;
  float Ss = 0.f;
  const ushortT* up = ubf + (size_t)(b*LL + tc*32)*1024 + d;
  #pragma unroll 2
  for(int t=0;t<32;t++){
    float a2 = bias;
    #pragma unroll
    for(int r=0;r<32;r++) a2 += sD[t][r]*wdt[r];
    float dtv = (a2 > 20.f) ? a2 : __logf(1.f + __expf(a2));
    float uv = bf2f(up[(size_t)t*1024]);
    float wt = dtv * uv;
    Ss += dtv;
    #pragma unroll
    for(int n=0;n<16;n++){
      float e = __expf(dtv * Ad[n]);
      h[n] = h[n]*e + wt*sD[t][32+n];
    }
  }
  size_t base4 = (size_t)(tc*8 + b)*4*1024 + d;
  #pragma unroll
  for(int n4=0;n4<4;n4++){
    Q4[base4 + n4*1024] = make_float4(h[n4*4], h[n4*4+1], h[n4*4+2], h[n4*4+3]);
    P4[base4 + n4*1024] = make_float4(__expf(Ss*Ad[n4*4]), __expf(Ss*Ad[n4*4+1]),
                                      __expf(Ss*Ad[n4*4+2]), __expf(Ss*Ad[n4*4+3]));
  }
}

// ------- combine chunks + z_last dot + C-dot + gating -> yv; 4 lanes per (b,d) unit -------
__global__ __launch_bounds__(256) void k_scan_combine(const float4* __restrict__ P4,
    const float4* __restrict__ Q4, const float* __restrict__ dbl,
    const ushortT* __restrict__ ubf, const ushortT* __restrict__ xbf,
    const ushortT* __restrict__ wbf, const float* __restrict__ Dp,
    float* __restrict__ yv){
  int tid = threadIdx.x;
  int unit = blockIdx.x*64 + (tid>>2);     // 8192 units
  int sub = tid & 3;
  int b = unit >> 10, d = unit & 1023;
  const ushortT* xr = xbf + (size_t)(b*LL + LL-1)*512 + sub*128;
  const ushortT* wr = wbf + (size_t)(1024 + d)*512 + sub*128;
  float zl = 0.f;
  #pragma unroll
  for(int k=0;k<128;k+=8){
    short8v xv = *(const short8v*)(xr + k);
    short8v wv = *(const short8v*)(wr + k);
    #pragma unroll
    for(int j=0;j<8;j++) zl += bf2f((ushortT)xv[j])*bf2f((ushortT)wv[j]);
  }
  zl += __shfl_xor(zl, 1);
  zl += __shfl_xor(zl, 2);
  float h0=0.f, h1=0.f, h2=0.f, h3=0.f;
  #pragma unroll
  for(int c=0;c<NTC;c++){
    size_t idx = (size_t)(c*8 + b)*4*1024 + sub*1024 + d;
    float4 pv = P4[idx];
    float4 qv = Q4[idx];
    h0 = pv.x*h0 + qv.x;
    h1 = pv.y*h1 + qv.y;
    h2 = pv.z*h2 + qv.z;
    h3 = pv.w*h3 + qv.w;
  }
  const float* Crow = dbl + (size_t)(b*LL + LL-1)*64 + 48 + sub*4;
  float y = Crow[0]*h0 + Crow[1]*h1 + Crow[2]*h2 + Crow[3]*h3;
  y += __shfl_xor(y, 1);
  y += __shfl_xor(y, 2);
  if(sub == 0){
    float ul = bf2f(ubf[(size_t)(b*LL + LL-1)*1024 + d]);
    float sz = zl / (1.f + __expf(-zl));
    yv[b*1024 + d] = (y + ul*Dp[d]) * sz;
  }
}

// ---------------- out_proj (last step only): xout[8][512] ----------------
__global__ __launch_bounds__(256) void k_outproj(const float* __restrict__ yv,
    const float* __restrict__ W, float* __restrict__ xout){
  int tid = threadIdx.x;
  int j = blockIdx.x*8 + (tid>>5);     // 64 blocks -> 512 outputs
  int ks = tid & 31;
  float a[8] = {};
  #pragma unroll
  for(int t=0;t<8;t++){
    int k = ks*4 + t*128;
    float4 wv = *(const float4*)(W + (size_t)j*1024 + k);
    #pragma unroll
    for(int b=0;b<8;b++){
      float4 xv = *(const float4*)(yv + b*1024 + k);
      a[b] += xv.x*wv.x + xv.y*wv.y + xv.z*wv.z + xv.w*wv.w;
    }
  }
  #pragma unroll
  for(int b=0;b<8;b++){
    #pragma unroll
    for(int o=16;o>=1;o>>=1) a[b] += __shfl_xor(a[b], o);
  }
  if(ks==0){
    #pragma unroll
    for(int b=0;b<8;b++) xout[b*512 + j] = a[b];
  }
}

// ---------------- head + denorm -> out[8][96][7] ----------------
__global__ __launch_bounds__(256) void k_head(const float* __restrict__ xout,
    const float* __restrict__ W, const float* __restrict__ hb,
    const float* __restrict__ mean, const float* __restrict__ stdv,
    float* __restrict__ out){
  int tid = threadIdx.x;
  int o = blockIdx.x*8 + (tid>>5);     // 84 blocks -> 672 outputs
  int ks = tid & 31;
  float a[8] = {};
  #pragma unroll
  for(int t=0;t<4;t++){
    int k = ks*4 + t*128;
    float4 wv = *(const float4*)(W + (size_t)o*512 + k);
    #pragma unroll
    for(int b=0;b<8;b++){
      float4 xv = *(const float4*)(xout + b*512 + k);
      a[b] += xv.x*wv.x + xv.y*wv.y + xv.z*wv.z + xv.w*wv.w;
    }
  }
  #pragma unroll
  for(int b=0;b<8;b++){
    #pragma unroll
    for(int oo=16;oo>=1;oo>>=1) a[b] += __shfl_xor(a[b], oo);
  }
  if(ks==0){
    int c = o % 7;
    #pragma unroll
    for(int b=0;b<8;b++){
      float v = a[b] + hb[o];
      out[b*NOUTC + o] = v * stdv[b*CIN + c] + mean[b*CIN + c];
    }
  }
}

extern "C" void kernel_launch(void* const* d_in, const int* in_sizes, int n_in,
                              void* d_out, int out_size, void* d_ws, size_t ws_size,
                              hipStream_t stream) {
  const float* x_enc   = (const float*)d_in[0];
  const float* x_mark  = (const float*)d_in[1];
  const float* tconvw  = (const float*)d_in[4];
  const float* tempw   = (const float*)d_in[5];
  const float* inprojw = (const float*)d_in[6];
  const float* convw   = (const float*)d_in[7];
  const float* convb   = (const float*)d_in[8];
  const float* xprojw  = (const float*)d_in[9];
  const float* dtw     = (const float*)d_in[10];
  const float* dtb     = (const float*)d_in[11];
  const float* alog    = (const float*)d_in[12];
  const float* dpar    = (const float*)d_in[13];
  const float* outw    = (const float*)d_in[14];
  const float* headw   = (const float*)d_in[15];
  const float* headb   = (const float*)d_in[16];

  float* ws    = (float*)d_ws;
  float* mean  = ws;                          // 64
  float* stdv  = ws + 64;                     // 64 -> 128
  ushortT* xbf = (ushortT*)(ws + 128);        // [4096][512]  bf16 -> 1,048,704
  ushortT* wbf = (ushortT*)(ws + 1048704);    // [2048][512]  bf16 -> 1,572,992
  ushortT* xpwbf=(ushortT*)(ws + 1572992);    // [64][1024]   bf16 -> 1,605,760
  ushortT* xpbf= (ushortT*)(ws + 1605760);    // [4096][1024] bf16 -> 3,702,912
  ushortT* ubf = (ushortT*)(ws + 3702912);    // [4096][1024] bf16 -> 5,800,064
  float* dbl   = ws + 5800064;                // [4096][64]   f32 -> 6,062,208
  float4* P4   = (float4*)(ws + 6062208);     // 524,288 float4 -> 8,159,360
  float4* Q4   = (float4*)(ws + 8159360);     // -> 10,256,512
  float* yv    = ws + 10256512;               // 8,192 -> 10,264,704
  float* xout  = ws + 10264704;               // 4,096 -> 10,268,800
  float* out   = (float*)d_out;

  k_prep_embed<<<1056, 512, 0, stream>>>(x_enc, x_mark, tconvw, tempw, inprojw, xprojw,
                                         (__hip_bfloat16*)xbf, wbf, xpwbf, mean, stdv);
  k_inproj_mfma<<<dim3(8, 32), 256, 0, stream>>>(xbf, wbf, xpbf);
  k_dwconv<<<256, 1024, 0, stream>>>(xpbf, convw, convb, ubf);
  k_xproj_mfma<<<128, 256, 0, stream>>>(ubf, xpwbf, dbl);
  k_scan_chunk<<<dim3(NTC, 4, 8), 256, 0, stream>>>(dbl, ubf, dtw, dtb, alog, P4, Q4);
  k_scan_combine<<<128, 256, 0, stream>>>(P4, Q4, dbl, ubf, xbf, wbf, dpar, yv);
  k_outproj<<<64, 256, 0, stream>>>(yv, outw, xout);
  k_head  <<<84, 256, 0, stream>>>(xout, headw, headb, mean, stdv, out);
}